// Round 10
// baseline (132.779 us; speedup 1.0000x reference)
//
#include <hip/hip_runtime.h>
#include <hip/hip_bf16.h>

typedef __bf16 bf16x8 __attribute__((ext_vector_type(8)));
typedef float  f32x4  __attribute__((ext_vector_type(4)));
typedef unsigned short u16;
typedef u16 ushort8_t __attribute__((ext_vector_type(8)));

#define PI_D 3.14159265358979323846

__device__ __forceinline__ float rfl_f(float x){
  return __builtin_bit_cast(float, __builtin_amdgcn_readfirstlane(__builtin_bit_cast(int, x)));
}
__device__ __forceinline__ u16 bf16_bits(float f){
  __bf16 b = (__bf16)f;
  return __builtin_bit_cast(u16, b);
}
__device__ __forceinline__ float bf2f(u16 u){
  return __builtin_bit_cast(float, ((unsigned)u) << 16);
}

// ---------------- K0: DCT / IDCT matrices (32x32 each, f32) ----------------
// Dm[k][i] = 2*cos(pi*k*(2i+1)/64)          (DCT, freq-major rows)
// Mm[i][k] = cos(pi*k*(2i+1)/64) * w[k]     (IDCT, space-major rows), w0=1/64 else 1/32
__global__ void k_init(float* __restrict__ Dm, float* __restrict__ Mm){
  for (int idx = threadIdx.x; idx < 1024; idx += 256){
    int r = idx >> 5, c = idx & 31;
    Dm[idx] = (float)(2.0 * cos(PI_D * (double)r * (double)(2*c+1) / 64.0));
    Mm[idx] = (float)(cos(PI_D * (double)c * (double)(2*r+1) / 64.0) * ((c==0)?0.5:1.0) / 32.0);
  }
}

// ---------------- KW2: wkb[kf][b][f][c] = sum_a dk[kf][a] * w[f][c][a*3+b]  (bf16) ----------------
__global__ __launch_bounds__(256) void k_wkb(const float* __restrict__ w,
                                             const float* __restrict__ Dm,
                                             u16* __restrict__ wkb){
  __shared__ float dks[32][3];
  int t = threadIdx.x;
  if (t < 96) dks[t/3][t%3] = Dm[(t/3)*32 + (t%3)];
  __syncthreads();
  int f = blockIdx.x, kf0 = blockIdx.y*4, c = t;
  const float* s = w + ((size_t)f*256 + c)*9;
  float wv9[9];
  #pragma unroll
  for (int j = 0; j < 9; ++j) wv9[j] = s[j];
  #pragma unroll
  for (int kq = 0; kq < 4; ++kq){
    int kf = kf0 + kq;
    float d0 = dks[kf][0], d1 = dks[kf][1], d2 = dks[kf][2];
    #pragma unroll
    for (int b = 0; b < 3; ++b){
      float v = d0*wv9[b] + d1*wv9[3+b] + d2*wv9[6+b];
      wkb[((size_t)(kf*3 + b) << 16) + (f << 8) + c] = bf16_bits(v);
    }
  }
}

// ---------------- KA2: fused DCT + transpose-write. Block = (n, 16 channels) ----------------
__global__ __launch_bounds__(256) void k_dct2(const float* __restrict__ x,
                                              const float* __restrict__ Dm,
                                              u16* __restrict__ Xt){
  __shared__ __bf16 Dmb[32][40];
  __shared__ float  xl[4][32*37];
  __shared__ __bf16 t1[4][32*40];
  __shared__ u16    st[1024][20];   // pad-20: row stride 40B = 10 dwords -> rotating banks
  int t = threadIdx.x;
  for (int idx = t; idx < 1024; idx += 256)
    Dmb[idx>>5][idx&31] = (__bf16)Dm[idx];
  __syncthreads();
  int wv = t >> 6, lane = t & 63, l4 = lane & 15, g = lane >> 4;
  bf16x8 dmf[2];
  dmf[0] = *(const bf16x8*)&Dmb[l4][g*8];
  dmf[1] = *(const bf16x8*)&Dmb[16+l4][g*8];
  int n = blockIdx.x, cb = blockIdx.y * 16;
  float* xw = xl[wv];
  __bf16* tw = t1[wv];
  f32x4 z = {0.f,0.f,0.f,0.f};
  for (int ci = 0; ci < 4; ++ci){
    int cl = wv*4 + ci;
    const float* xs = x + ((size_t)(n*256 + cb + cl)) * 1024;
    #pragma unroll
    for (int jr = 0; jr < 4; ++jr){
      int e = jr*256 + lane*4;
      float4 v = *(const float4*)(xs + e);
      float* p = xw + (e>>5)*37 + (e&31);
      p[0]=v.x; p[1]=v.y; p[2]=v.z; p[3]=v.w;
    }
    bf16x8 bf[2];
    #pragma unroll
    for (int nn = 0; nn < 2; ++nn){
      #pragma unroll
      for (int jj = 0; jj < 8; ++jj)
        bf[nn][jj] = (__bf16)xw[(g*8+jj)*37 + nn*16 + l4];
    }
    #pragma unroll
    for (int m = 0; m < 2; ++m){
      #pragma unroll
      for (int nn = 0; nn < 2; ++nn){
        f32x4 d = __builtin_amdgcn_mfma_f32_16x16x32_bf16(dmf[m], bf[nn], z, 0,0,0);
        #pragma unroll
        for (int r = 0; r < 4; ++r)
          tw[(m*16 + g*4 + r)*40 + nn*16 + l4] = (__bf16)d[r];
      }
    }
    bf16x8 a2[2];
    a2[0] = *(const bf16x8*)&tw[(l4)*40 + g*8];
    a2[1] = *(const bf16x8*)&tw[(16+l4)*40 + g*8];
    #pragma unroll
    for (int m2 = 0; m2 < 2; ++m2){
      #pragma unroll
      for (int nn2 = 0; nn2 < 2; ++nn2){
        f32x4 d = __builtin_amdgcn_mfma_f32_16x16x32_bf16(a2[m2], dmf[nn2], z, 0,0,0);
        #pragma unroll
        for (int r = 0; r < 4; ++r){
          int kk = m2*16 + g*4 + r, ll = nn2*16 + l4;
          st[kk*32 + ll][cl] = bf16_bits(d[r]);
        }
      }
    }
  }
  __syncthreads();
  #pragma unroll
  for (int rr = 0; rr < 8; ++rr){
    int kl = rr*128 + (t >> 1), half = t & 1;
    ushort4 v0 = *(const ushort4*)&st[kl][half*8];
    ushort4 v1 = *(const ushort4*)&st[kl][half*8 + 4];
    ushort8_t o;
    o[0]=v0.x; o[1]=v0.y; o[2]=v0.z; o[3]=v0.w;
    o[4]=v1.x; o[5]=v1.y; o[6]=v1.z; o[7]=v1.w;
    *(ushort8_t*)(Xt + (size_t)kl*16384 + (size_t)n*256 + cb + half*8) = o;
  }
}

// ---------------- KC: channel mix, wave-independent, barrier-free, 32f/wave ----------------
// Block = 4 waves; wave wv owns (kl = blockIdx.x, f-slice = blockIdx.y*128 + wv*32), 64n x 32f.
// acc[4][2] = 32 AGPR (vs round-9's 64) -> ~120 unified regs -> 4 waves/SIMD occupancy.
// B generated IN REGISTERS from wkb (K = sum_b dl[b]*wkb[kf][b][f][c]) — no LDS, no syncthreads.
// Same arithmetic expression as rounds 8/9 => identical results.
__global__ __launch_bounds__(256) void k_mix(const u16* __restrict__ Xt,
                                             const u16* __restrict__ wkb,
                                             const float* __restrict__ Dm,
                                             u16* __restrict__ R){
  int t = threadIdx.x;
  int lane = t & 63, wv = t >> 6;
  int kl = blockIdx.x;
  int fs = blockIdx.y * 128 + wv * 32;   // f-slice base (32 f per wave)
  int kf = kl >> 5, li = kl & 31;
  int l4 = lane & 15, g = lane >> 4;
  float dl0 = rfl_f(Dm[li*32 + 0]);
  float dl1 = rfl_f(Dm[li*32 + 1]);
  float dl2 = rfl_f(Dm[li*32 + 2]);
  // A: Xt[kl][mt*16+l4][cc*32 + g*8 ..+8]
  const u16* xbase = Xt + (size_t)kl*16384 + (size_t)l4*256 + g*8;
  // B source: wkb[kf][b][fs + nn*16 + l4][cc*32 + g*8 ..+8]
  const u16* wbase = wkb + ((size_t)(kf*3) << 16) + ((size_t)(fs + l4) << 8) + g*8;
  f32x4 acc[4][2];
  #pragma unroll
  for (int mt = 0; mt < 4; ++mt){
    #pragma unroll
    for (int nn = 0; nn < 2; ++nn){ f32x4 z={0.f,0.f,0.f,0.f}; acc[mt][nn]=z; }
  }
  for (int cc = 0; cc < 8; ++cc){
    bf16x8 af[4];
    #pragma unroll
    for (int mt = 0; mt < 4; ++mt)
      af[mt] = *(const bf16x8*)(xbase + mt*16*256 + cc*32);
    bf16x8 bfr[2];
    #pragma unroll
    for (int nn = 0; nn < 2; ++nn){
      const u16* wp = wbase + (nn*16 << 8) + cc*32;
      ushort8_t q0 = *(const ushort8_t*)(wp);
      ushort8_t q1 = *(const ushort8_t*)(wp + 65536);
      ushort8_t q2 = *(const ushort8_t*)(wp + 131072);
      #pragma unroll
      for (int j = 0; j < 8; ++j){
        float s = dl0*bf2f(q0[j]) + dl1*bf2f(q1[j]) + dl2*bf2f(q2[j]);
        bfr[nn][j] = (__bf16)s;
      }
    }
    #pragma unroll
    for (int mt = 0; mt < 4; ++mt){
      #pragma unroll
      for (int nn = 0; nn < 2; ++nn)
        acc[mt][nn] = __builtin_amdgcn_mfma_f32_16x16x32_bf16(af[mt], bfr[nn], acc[mt][nn], 0,0,0);
    }
  }
  // epilogue: R[kl][n][f] bf16 — f contiguous segments
  u16* rbase = R + ((size_t)kl << 14) + fs;
  #pragma unroll
  for (int mt = 0; mt < 4; ++mt){
    #pragma unroll
    for (int nn = 0; nn < 2; ++nn){
      #pragma unroll
      for (int r = 0; r < 4; ++r){
        int n = mt*16 + g*4 + r;
        rbase[(size_t)n*256 + nn*16 + l4] = bf16_bits(acc[mt][nn][r]);
      }
    }
  }
}

// ---------------- KD2: fused gather-transpose + IDCT + crop. Block = (n, 16 f) ----------------
__global__ __launch_bounds__(256) void k_idct2(const u16* __restrict__ R,
                                               const float* __restrict__ Mm,
                                               float* __restrict__ out){
  __shared__ __bf16 Mmb[32][40];
  __shared__ u16    st[1024][20];
  __shared__ __bf16 t2[4][32*40];
  int t = threadIdx.x;
  for (int idx = t; idx < 1024; idx += 256)
    Mmb[idx>>5][idx&31] = (__bf16)Mm[idx];
  int n = blockIdx.x, fbb = blockIdx.y * 16;
  #pragma unroll
  for (int rr = 0; rr < 8; ++rr){
    int kl = rr*128 + (t >> 1), half = t & 1;
    ushort8_t v = *(const ushort8_t*)(R + (size_t)kl*16384 + (size_t)n*256 + fbb + half*8);
    ushort4 a, b;
    a.x=v[0]; a.y=v[1]; a.z=v[2]; a.w=v[3];
    b.x=v[4]; b.y=v[5]; b.z=v[6]; b.w=v[7];
    *(ushort4*)&st[kl][half*8]     = a;
    *(ushort4*)&st[kl][half*8 + 4] = b;
  }
  __syncthreads();
  int wv = t>>6, lane = t&63, l4 = lane&15, g = lane>>4;
  bf16x8 mmf[2];
  mmf[0] = *(const bf16x8*)&Mmb[l4][g*8];
  mmf[1] = *(const bf16x8*)&Mmb[16+l4][g*8];
  f32x4 z = {0.f,0.f,0.f,0.f};
  __bf16* tw = t2[wv];
  for (int ci = 0; ci < 4; ++ci){
    int fl = wv*4 + ci;
    bf16x8 bfr[2];
    #pragma unroll
    for (int nn = 0; nn < 2; ++nn){
      #pragma unroll
      for (int jj = 0; jj < 8; ++jj)
        bfr[nn][jj] = __builtin_bit_cast(__bf16, st[(g*8+jj)*32 + nn*16 + l4][fl]);
    }
    #pragma unroll
    for (int m = 0; m < 2; ++m){
      #pragma unroll
      for (int nn = 0; nn < 2; ++nn){
        f32x4 d = __builtin_amdgcn_mfma_f32_16x16x32_bf16(mmf[m], bfr[nn], z, 0,0,0);
        #pragma unroll
        for (int r = 0; r < 4; ++r)
          tw[(m*16 + g*4 + r)*40 + nn*16 + l4] = (__bf16)d[r];
      }
    }
    bf16x8 a2[2];
    a2[0] = *(const bf16x8*)&tw[l4*40 + g*8];
    a2[1] = *(const bf16x8*)&tw[(16+l4)*40 + g*8];
    float* oo = out + (size_t)(n*256 + fbb + fl)*900;
    #pragma unroll
    for (int m2 = 0; m2 < 2; ++m2){
      #pragma unroll
      for (int nn2 = 0; nn2 < 2; ++nn2){
        f32x4 d = __builtin_amdgcn_mfma_f32_16x16x32_bf16(a2[m2], mmf[nn2], z, 0,0,0);
        #pragma unroll
        for (int r = 0; r < 4; ++r){
          int h = m2*16 + g*4 + r, w2 = nn2*16 + l4;
          if (h < 30 && w2 < 30) oo[h*30 + w2] = d[r];
        }
      }
    }
  }
}

// ---------------- launch ----------------
// ws layout (bytes) — peak 79,699,968:
//   Dm   @ 0          (4 KB)
//   Mm   @ 4096       (4 KB)
//   Xt   @ 8192       (33,554,432)   [kl][n][c] bf16
//   R    @ 33562624   (33,554,432)   [kl][n][f] bf16
//   wkb  @ 67117056   (12,582,912)   [kf][b][f][c] bf16
extern "C" void kernel_launch(void* const* d_in, const int* in_sizes, int n_in,
                              void* d_out, int out_size, void* d_ws, size_t ws_size,
                              hipStream_t stream){
  (void)in_sizes; (void)n_in; (void)out_size; (void)ws_size;
  const float* x  = (const float*)d_in[0];
  const float* w  = (const float*)d_in[1];
  float* out = (float*)d_out;
  char* ws = (char*)d_ws;
  float* Dm = (float*)(ws + 0);
  float* Mm = (float*)(ws + 4096);
  u16* Xt   = (u16*)(ws + 8192);
  u16* R    = (u16*)(ws + 33562624);
  u16* wkb  = (u16*)(ws + 67117056);

  hipLaunchKernelGGL(k_init,  dim3(1),        dim3(256), 0, stream, Dm, Mm);
  hipLaunchKernelGGL(k_wkb,   dim3(256,8),    dim3(256), 0, stream, w, Dm, wkb);
  hipLaunchKernelGGL(k_dct2,  dim3(64,16),    dim3(256), 0, stream, x, Dm, Xt);
  hipLaunchKernelGGL(k_mix,   dim3(1024,2),   dim3(256), 0, stream, Xt, wkb, Dm, R);
  hipLaunchKernelGGL(k_idct2, dim3(64,16),    dim3(256), 0, stream, R, Mm, out);
}

// Round 11
// 83.364 us; speedup vs baseline: 1.5928x; 1.5928x over previous
//
#include <hip/hip_runtime.h>
#include <hip/hip_bf16.h>

typedef __bf16 bf16x8 __attribute__((ext_vector_type(8)));
typedef float  f32x4  __attribute__((ext_vector_type(4)));
typedef unsigned short u16;
typedef u16 ushort8_t __attribute__((ext_vector_type(8)));

#define PI_D 3.14159265358979323846

__device__ __forceinline__ float rfl_f(float x){
  return __builtin_bit_cast(float, __builtin_amdgcn_readfirstlane(__builtin_bit_cast(int, x)));
}
__device__ __forceinline__ u16 bf16_bits(float f){
  __bf16 b = (__bf16)f;
  return __builtin_bit_cast(u16, b);
}
__device__ __forceinline__ float bf2f(u16 u){
  return __builtin_bit_cast(float, ((unsigned)u) << 16);
}

// ---------------- K0: DCT / IDCT matrices (32x32 each, f32) ----------------
// Dm[k][i] = 2*cos(pi*k*(2i+1)/64)          (DCT, freq-major rows)
// Mm[i][k] = cos(pi*k*(2i+1)/64) * w[k]     (IDCT, space-major rows), w0=1/64 else 1/32
__global__ void k_init(float* __restrict__ Dm, float* __restrict__ Mm){
  for (int idx = threadIdx.x; idx < 1024; idx += 256){
    int r = idx >> 5, c = idx & 31;
    Dm[idx] = (float)(2.0 * cos(PI_D * (double)r * (double)(2*c+1) / 64.0));
    Mm[idx] = (float)(cos(PI_D * (double)c * (double)(2*r+1) / 64.0) * ((c==0)?0.5:1.0) / 32.0);
  }
}

// ---------------- KW2: wkb[kf][b][f][c] = sum_a dk[kf][a] * w[f][c][a*3+b]  (bf16) ----------------
__global__ __launch_bounds__(256) void k_wkb(const float* __restrict__ w,
                                             const float* __restrict__ Dm,
                                             u16* __restrict__ wkb){
  __shared__ float dks[32][3];
  int t = threadIdx.x;
  if (t < 96) dks[t/3][t%3] = Dm[(t/3)*32 + (t%3)];
  __syncthreads();
  int f = blockIdx.x, kf0 = blockIdx.y*4, c = t;
  const float* s = w + ((size_t)f*256 + c)*9;
  float wv9[9];
  #pragma unroll
  for (int j = 0; j < 9; ++j) wv9[j] = s[j];
  #pragma unroll
  for (int kq = 0; kq < 4; ++kq){
    int kf = kf0 + kq;
    float d0 = dks[kf][0], d1 = dks[kf][1], d2 = dks[kf][2];
    #pragma unroll
    for (int b = 0; b < 3; ++b){
      float v = d0*wv9[b] + d1*wv9[3+b] + d2*wv9[6+b];
      wkb[((size_t)(kf*3 + b) << 16) + (f << 8) + c] = bf16_bits(v);
    }
  }
}

// ---------------- KA2: fused DCT + transpose-write. Block = (n, 16 channels) ----------------
__global__ __launch_bounds__(256) void k_dct2(const float* __restrict__ x,
                                              const float* __restrict__ Dm,
                                              u16* __restrict__ Xt){
  __shared__ __bf16 Dmb[32][40];
  __shared__ float  xl[4][32*37];
  __shared__ __bf16 t1[4][32*40];
  __shared__ u16    st[1024][20];   // pad-20: row stride 40B = 10 dwords -> rotating banks
  int t = threadIdx.x;
  for (int idx = t; idx < 1024; idx += 256)
    Dmb[idx>>5][idx&31] = (__bf16)Dm[idx];
  __syncthreads();
  int wv = t >> 6, lane = t & 63, l4 = lane & 15, g = lane >> 4;
  bf16x8 dmf[2];
  dmf[0] = *(const bf16x8*)&Dmb[l4][g*8];
  dmf[1] = *(const bf16x8*)&Dmb[16+l4][g*8];
  int n = blockIdx.x, cb = blockIdx.y * 16;
  float* xw = xl[wv];
  __bf16* tw = t1[wv];
  f32x4 z = {0.f,0.f,0.f,0.f};
  for (int ci = 0; ci < 4; ++ci){
    int cl = wv*4 + ci;
    const float* xs = x + ((size_t)(n*256 + cb + cl)) * 1024;
    #pragma unroll
    for (int jr = 0; jr < 4; ++jr){
      int e = jr*256 + lane*4;
      float4 v = *(const float4*)(xs + e);
      float* p = xw + (e>>5)*37 + (e&31);
      p[0]=v.x; p[1]=v.y; p[2]=v.z; p[3]=v.w;
    }
    bf16x8 bf[2];
    #pragma unroll
    for (int nn = 0; nn < 2; ++nn){
      #pragma unroll
      for (int jj = 0; jj < 8; ++jj)
        bf[nn][jj] = (__bf16)xw[(g*8+jj)*37 + nn*16 + l4];
    }
    #pragma unroll
    for (int m = 0; m < 2; ++m){
      #pragma unroll
      for (int nn = 0; nn < 2; ++nn){
        f32x4 d = __builtin_amdgcn_mfma_f32_16x16x32_bf16(dmf[m], bf[nn], z, 0,0,0);
        #pragma unroll
        for (int r = 0; r < 4; ++r)
          tw[(m*16 + g*4 + r)*40 + nn*16 + l4] = (__bf16)d[r];
      }
    }
    bf16x8 a2[2];
    a2[0] = *(const bf16x8*)&tw[(l4)*40 + g*8];
    a2[1] = *(const bf16x8*)&tw[(16+l4)*40 + g*8];
    #pragma unroll
    for (int m2 = 0; m2 < 2; ++m2){
      #pragma unroll
      for (int nn2 = 0; nn2 < 2; ++nn2){
        f32x4 d = __builtin_amdgcn_mfma_f32_16x16x32_bf16(a2[m2], dmf[nn2], z, 0,0,0);
        #pragma unroll
        for (int r = 0; r < 4; ++r){
          int kk = m2*16 + g*4 + r, ll = nn2*16 + l4;
          st[kk*32 + ll][cl] = bf16_bits(d[r]);
        }
      }
    }
  }
  __syncthreads();
  #pragma unroll
  for (int rr = 0; rr < 8; ++rr){
    int kl = rr*128 + (t >> 1), half = t & 1;
    ushort4 v0 = *(const ushort4*)&st[kl][half*8];
    ushort4 v1 = *(const ushort4*)&st[kl][half*8 + 4];
    ushort8_t o;
    o[0]=v0.x; o[1]=v0.y; o[2]=v0.z; o[3]=v0.w;
    o[4]=v1.x; o[5]=v1.y; o[6]=v1.z; o[7]=v1.w;
    *(ushort8_t*)(Xt + (size_t)kl*16384 + (size_t)n*256 + cb + half*8) = o;
  }
}

// ---------------- KC: channel mix. Per block: 4 kl x 64 n x 64 f, K-loop over c ----------------
// R[kl][n][f] = sum_c X[kl][n][c] * K[f][c](kl),  K = sum_b dl[i][b] * wkb[kf][b][f][c].
// Direct-A global->reg; B double-buffered in LDS -> ONE barrier per cc; rolling wkb prefetch.
// XCD-chunked swizzle (HW round-robin bid&7 -> XCD): XCD x owns klg in [32x, 32x+32),
// f-siblings consecutive -> Xt rows fetched once/XCD, wkb slice (4 kf = 1.6 MB) L2-resident.
__global__ __launch_bounds__(512) void k_mix(const u16* __restrict__ Xt,
                                             const u16* __restrict__ wkb,
                                             const float* __restrict__ Dm,
                                             u16* __restrict__ R){
  __shared__ __bf16 Bl[2][4][64][40];
  int t = threadIdx.x;
  int orig = blockIdx.x;               // 0..1023, XCD = orig & 7 (round-robin)
  int wid  = (orig & 7)*128 + (orig >> 3);   // chunked: contiguous work per XCD
  int klg  = wid >> 2;                 // 0..255
  int fb   = (wid & 3) * 64;           // f base — siblings temporally adjacent
  int kl0 = klg * 4;
  int kf  = kl0 >> 5;                  // k (row frequency), shared by the 4 kl
  int lb  = kl0 & 31;                  // l base
  float dl[4][3];
  #pragma unroll
  for (int i = 0; i < 4; ++i){
    #pragma unroll
    for (int b = 0; b < 3; ++b) dl[i][b] = rfl_f(Dm[(lb+i)*32 + b]);
  }
  int lane = t & 63, wv = t >> 6;
  int kli = wv & 3, nh = wv >> 2;
  int l4 = lane & 15, g = lane >> 4;
  int rowi = t >> 3;             // 0..63 : f-local row for B-gen
  int cq   = t & 7;              // c-quad within 32-wide chunk
  f32x4 acc[2][4];
  #pragma unroll
  for (int m = 0; m < 2; ++m){
    #pragma unroll
    for (int nn = 0; nn < 4; ++nn){ f32x4 z={0.f,0.f,0.f,0.f}; acc[m][nn]=z; }
  }
  // per-lane global A-frag base: Xt[kl0+kli][nh*32 + l4][g*8]  (+16*256 for m=1)
  const u16* xb = Xt + (size_t)(kl0 + kli)*16384 + (size_t)(nh*32 + l4)*256 + g*8;
  const u16* wb = wkb + ((size_t)(kf*3) << 16) + ((fb + rowi) << 8) + cq*4;
  // prologue: wq[b] = wkb[kf][b][fb+rowi][cq*4 .. +3] for cc=0
  ushort4 wq[3];
  #pragma unroll
  for (int b = 0; b < 3; ++b) wq[b] = *(const ushort4*)(wb + ((size_t)b << 16));
  for (int cc = 0; cc < 8; ++cc){
    int p = cc & 1;
    // A-frags for THIS cc: latency hidden behind gen + barrier
    bf16x8 afc[2];
    afc[0] = *(const bf16x8*)(xb + cc*32);
    afc[1] = *(const bf16x8*)(xb + cc*32 + 16*256);
    // convert current wkb quads to f32; rolling reload for cc+1
    float tf[3][4];
    #pragma unroll
    for (int b = 0; b < 3; ++b){
      tf[b][0] = bf2f(wq[b].x); tf[b][1] = bf2f(wq[b].y);
      tf[b][2] = bf2f(wq[b].z); tf[b][3] = bf2f(wq[b].w);
    }
    if (cc < 7){
      const u16* wn = wb + (cc + 1)*32;
      #pragma unroll
      for (int b = 0; b < 3; ++b) wq[b] = *(const ushort4*)(wn + ((size_t)b << 16));
    }
    #pragma unroll
    for (int i = 0; i < 4; ++i){
      float s0 = dl[i][0]*tf[0][0] + dl[i][1]*tf[1][0] + dl[i][2]*tf[2][0];
      float s1 = dl[i][0]*tf[0][1] + dl[i][1]*tf[1][1] + dl[i][2]*tf[2][1];
      float s2 = dl[i][0]*tf[0][2] + dl[i][1]*tf[1][2] + dl[i][2]*tf[2][2];
      float s3 = dl[i][0]*tf[0][3] + dl[i][1]*tf[1][3] + dl[i][2]*tf[2][3];
      ushort4 pv;
      pv.x = bf16_bits(s0); pv.y = bf16_bits(s1);
      pv.z = bf16_bits(s2); pv.w = bf16_bits(s3);
      *(ushort4*)((u16*)&Bl[p][i][rowi][cq*4]) = pv;
    }
    __syncthreads();
    bf16x8 bfr[4];
    #pragma unroll
    for (int nn = 0; nn < 4; ++nn)
      bfr[nn] = *(const bf16x8*)&Bl[p][kli][nn*16 + l4][g*8];
    #pragma unroll
    for (int m = 0; m < 2; ++m){
      #pragma unroll
      for (int nn = 0; nn < 4; ++nn)
        acc[m][nn] = __builtin_amdgcn_mfma_f32_16x16x32_bf16(afc[m], bfr[nn], acc[m][nn], 0,0,0);
    }
  }
  // epilogue: R[kl][n][f] bf16 — f contiguous, 4x32B segments per store instr
  int kl = kl0 + kli;
  #pragma unroll
  for (int m = 0; m < 2; ++m){
    #pragma unroll
    for (int nn = 0; nn < 4; ++nn){
      #pragma unroll
      for (int r = 0; r < 4; ++r){
        int n = nh*32 + m*16 + g*4 + r;
        R[((size_t)kl*64 + n)*256 + fb + nn*16 + l4] = bf16_bits(acc[m][nn][r]);
      }
    }
  }
}

// ---------------- KD2: fused gather-transpose + IDCT + crop. Block = (n, 16 f) ----------------
__global__ __launch_bounds__(256) void k_idct2(const u16* __restrict__ R,
                                               const float* __restrict__ Mm,
                                               float* __restrict__ out){
  __shared__ __bf16 Mmb[32][40];
  __shared__ u16    st[1024][20];
  __shared__ __bf16 t2[4][32*40];
  int t = threadIdx.x;
  for (int idx = t; idx < 1024; idx += 256)
    Mmb[idx>>5][idx&31] = (__bf16)Mm[idx];
  int n = blockIdx.x, fbb = blockIdx.y * 16;
  #pragma unroll
  for (int rr = 0; rr < 8; ++rr){
    int kl = rr*128 + (t >> 1), half = t & 1;
    ushort8_t v = *(const ushort8_t*)(R + (size_t)kl*16384 + (size_t)n*256 + fbb + half*8);
    ushort4 a, b;
    a.x=v[0]; a.y=v[1]; a.z=v[2]; a.w=v[3];
    b.x=v[4]; b.y=v[5]; b.z=v[6]; b.w=v[7];
    *(ushort4*)&st[kl][half*8]     = a;
    *(ushort4*)&st[kl][half*8 + 4] = b;
  }
  __syncthreads();
  int wv = t>>6, lane = t&63, l4 = lane&15, g = lane>>4;
  bf16x8 mmf[2];
  mmf[0] = *(const bf16x8*)&Mmb[l4][g*8];
  mmf[1] = *(const bf16x8*)&Mmb[16+l4][g*8];
  f32x4 z = {0.f,0.f,0.f,0.f};
  __bf16* tw = t2[wv];
  for (int ci = 0; ci < 4; ++ci){
    int fl = wv*4 + ci;
    bf16x8 bfr[2];
    #pragma unroll
    for (int nn = 0; nn < 2; ++nn){
      #pragma unroll
      for (int jj = 0; jj < 8; ++jj)
        bfr[nn][jj] = __builtin_bit_cast(__bf16, st[(g*8+jj)*32 + nn*16 + l4][fl]);
    }
    #pragma unroll
    for (int m = 0; m < 2; ++m){
      #pragma unroll
      for (int nn = 0; nn < 2; ++nn){
        f32x4 d = __builtin_amdgcn_mfma_f32_16x16x32_bf16(mmf[m], bfr[nn], z, 0,0,0);
        #pragma unroll
        for (int r = 0; r < 4; ++r)
          tw[(m*16 + g*4 + r)*40 + nn*16 + l4] = (__bf16)d[r];
      }
    }
    bf16x8 a2[2];
    a2[0] = *(const bf16x8*)&tw[l4*40 + g*8];
    a2[1] = *(const bf16x8*)&tw[(16+l4)*40 + g*8];
    float* oo = out + (size_t)(n*256 + fbb + fl)*900;
    #pragma unroll
    for (int m2 = 0; m2 < 2; ++m2){
      #pragma unroll
      for (int nn2 = 0; nn2 < 2; ++nn2){
        f32x4 d = __builtin_amdgcn_mfma_f32_16x16x32_bf16(a2[m2], mmf[nn2], z, 0,0,0);
        #pragma unroll
        for (int r = 0; r < 4; ++r){
          int h = m2*16 + g*4 + r, w2 = nn2*16 + l4;
          if (h < 30 && w2 < 30) oo[h*30 + w2] = d[r];
        }
      }
    }
  }
}

// ---------------- launch ----------------
// ws layout (bytes) — peak 79,699,968:
//   Dm   @ 0          (4 KB)
//   Mm   @ 4096       (4 KB)
//   Xt   @ 8192       (33,554,432)   [kl][n][c] bf16
//   R    @ 33562624   (33,554,432)   [kl][n][f] bf16
//   wkb  @ 67117056   (12,582,912)   [kf][b][f][c] bf16
extern "C" void kernel_launch(void* const* d_in, const int* in_sizes, int n_in,
                              void* d_out, int out_size, void* d_ws, size_t ws_size,
                              hipStream_t stream){
  (void)in_sizes; (void)n_in; (void)out_size; (void)ws_size;
  const float* x  = (const float*)d_in[0];
  const float* w  = (const float*)d_in[1];
  float* out = (float*)d_out;
  char* ws = (char*)d_ws;
  float* Dm = (float*)(ws + 0);
  float* Mm = (float*)(ws + 4096);
  u16* Xt   = (u16*)(ws + 8192);
  u16* R    = (u16*)(ws + 33562624);
  u16* wkb  = (u16*)(ws + 67117056);

  hipLaunchKernelGGL(k_init,  dim3(1),        dim3(256), 0, stream, Dm, Mm);
  hipLaunchKernelGGL(k_wkb,   dim3(256,8),    dim3(256), 0, stream, w, Dm, wkb);
  hipLaunchKernelGGL(k_dct2,  dim3(64,16),    dim3(256), 0, stream, x, Dm, Xt);
  hipLaunchKernelGGL(k_mix,   dim3(1024),     dim3(512), 0, stream, Xt, wkb, Dm, R);
  hipLaunchKernelGGL(k_idct2, dim3(64,16),    dim3(256), 0, stream, R, Mm, out);
}

// Round 12
// 82.157 us; speedup vs baseline: 1.6162x; 1.0147x over previous
//
#include <hip/hip_runtime.h>
#include <hip/hip_bf16.h>

typedef __bf16 bf16x8 __attribute__((ext_vector_type(8)));
typedef float  f32x4  __attribute__((ext_vector_type(4)));
typedef unsigned short u16;
typedef u16 ushort8_t __attribute__((ext_vector_type(8)));

#define PI_D 3.14159265358979323846

__device__ __forceinline__ float rfl_f(float x){
  return __builtin_bit_cast(float, __builtin_amdgcn_readfirstlane(__builtin_bit_cast(int, x)));
}
__device__ __forceinline__ u16 bf16_bits(float f){
  __bf16 b = (__bf16)f;
  return __builtin_bit_cast(u16, b);
}
__device__ __forceinline__ float bf2f(u16 u){
  return __builtin_bit_cast(float, ((unsigned)u) << 16);
}

// ---------------- K0: DCT / IDCT matrices (32x32 each, f32) ----------------
// Dm[k][i] = 2*cos(pi*k*(2i+1)/64)          (DCT, freq-major rows)
// Mm[i][k] = cos(pi*k*(2i+1)/64) * w[k]     (IDCT, space-major rows), w0=1/64 else 1/32
__global__ void k_init(float* __restrict__ Dm, float* __restrict__ Mm){
  for (int idx = threadIdx.x; idx < 1024; idx += 256){
    int r = idx >> 5, c = idx & 31;
    Dm[idx] = (float)(2.0 * cos(PI_D * (double)r * (double)(2*c+1) / 64.0));
    Mm[idx] = (float)(cos(PI_D * (double)c * (double)(2*r+1) / 64.0) * ((c==0)?0.5:1.0) / 32.0);
  }
}

// ---------------- KW2: wkb[kf][b][f][c] = sum_a dk[kf][a] * w[f][c][a*3+b]  (bf16) ----------------
__global__ __launch_bounds__(256) void k_wkb(const float* __restrict__ w,
                                             const float* __restrict__ Dm,
                                             u16* __restrict__ wkb){
  __shared__ float dks[32][3];
  int t = threadIdx.x;
  if (t < 96) dks[t/3][t%3] = Dm[(t/3)*32 + (t%3)];
  __syncthreads();
  int f = blockIdx.x, kf0 = blockIdx.y*4, c = t;
  const float* s = w + ((size_t)f*256 + c)*9;
  float wv9[9];
  #pragma unroll
  for (int j = 0; j < 9; ++j) wv9[j] = s[j];
  #pragma unroll
  for (int kq = 0; kq < 4; ++kq){
    int kf = kf0 + kq;
    float d0 = dks[kf][0], d1 = dks[kf][1], d2 = dks[kf][2];
    #pragma unroll
    for (int b = 0; b < 3; ++b){
      float v = d0*wv9[b] + d1*wv9[3+b] + d2*wv9[6+b];
      wkb[((size_t)(kf*3 + b) << 16) + (f << 8) + c] = bf16_bits(v);
    }
  }
}

// ---------------- KA2: fused DCT + transpose-write, W-first phase order ----------------
// X = DH·x·DW^T computed as (x·DW^T) then DH·(...). A-frag for phase 1 = x ROWS:
// contiguous coalesced global loads, no LDS staging of x. LDS 53.8 KB -> 3 blocks/CU.
__global__ __launch_bounds__(256) void k_dct2(const float* __restrict__ x,
                                              const float* __restrict__ Dm,
                                              u16* __restrict__ Xt){
  __shared__ __bf16 Dmb[32][40];
  __shared__ __bf16 t1[4][32*40];
  __shared__ u16    st[1024][20];   // pad-20: row stride 40B = 10 dwords -> rotating banks
  int t = threadIdx.x;
  for (int idx = t; idx < 1024; idx += 256)
    Dmb[idx>>5][idx&31] = (__bf16)Dm[idx];
  __syncthreads();
  int wv = t >> 6, lane = t & 63, l4 = lane & 15, g = lane >> 4;
  bf16x8 dmf[2];
  dmf[0] = *(const bf16x8*)&Dmb[l4][g*8];
  dmf[1] = *(const bf16x8*)&Dmb[16+l4][g*8];
  int n = blockIdx.x, cb = blockIdx.y * 16;
  __bf16* tw = t1[wv];
  f32x4 z = {0.f,0.f,0.f,0.f};
  for (int ci = 0; ci < 4; ++ci){
    int cl = wv*4 + ci;
    const float* xs = x + ((size_t)(n*256 + cb + cl)) * 1024;
    // phase 1: T1'[h][lf] = sum_w x[h][w]*DW[lf][w].  A = x rows (direct global), B = Dm frag.
    bf16x8 af[2];
    #pragma unroll
    for (int m = 0; m < 2; ++m){
      const float* xr = xs + (m*16 + l4)*32 + g*8;
      float4 v0 = *(const float4*)(xr);
      float4 v1 = *(const float4*)(xr + 4);
      af[m][0]=(__bf16)v0.x; af[m][1]=(__bf16)v0.y; af[m][2]=(__bf16)v0.z; af[m][3]=(__bf16)v0.w;
      af[m][4]=(__bf16)v1.x; af[m][5]=(__bf16)v1.y; af[m][6]=(__bf16)v1.z; af[m][7]=(__bf16)v1.w;
    }
    #pragma unroll
    for (int m = 0; m < 2; ++m){
      #pragma unroll
      for (int nn = 0; nn < 2; ++nn){
        f32x4 d = __builtin_amdgcn_mfma_f32_16x16x32_bf16(af[m], dmf[nn], z, 0,0,0);
        // d[r] = T1'[h = m*16+g*4+r][lf = nn*16+l4]; store transposed: t1[lf][h]
        #pragma unroll
        for (int r = 0; r < 4; ++r)
          tw[(nn*16 + l4)*40 + m*16 + g*4 + r] = (__bf16)d[r];
      }
    }
    // phase 2: X[kf][lf] = sum_h DH[kf][h]*T1'[h][lf].  A = Dm frag, B = t1[lf][g*8..] (b128).
    bf16x8 b2[2];
    b2[0] = *(const bf16x8*)&tw[(l4)*40 + g*8];
    b2[1] = *(const bf16x8*)&tw[(16+l4)*40 + g*8];
    #pragma unroll
    for (int m2 = 0; m2 < 2; ++m2){
      #pragma unroll
      for (int nn2 = 0; nn2 < 2; ++nn2){
        f32x4 d = __builtin_amdgcn_mfma_f32_16x16x32_bf16(dmf[m2], b2[nn2], z, 0,0,0);
        #pragma unroll
        for (int r = 0; r < 4; ++r){
          int kk = m2*16 + g*4 + r, ll = nn2*16 + l4;
          st[kk*32 + ll][cl] = bf16_bits(d[r]);
        }
      }
    }
  }
  __syncthreads();
  #pragma unroll
  for (int rr = 0; rr < 8; ++rr){
    int kl = rr*128 + (t >> 1), half = t & 1;
    ushort4 v0 = *(const ushort4*)&st[kl][half*8];
    ushort4 v1 = *(const ushort4*)&st[kl][half*8 + 4];
    ushort8_t o;
    o[0]=v0.x; o[1]=v0.y; o[2]=v0.z; o[3]=v0.w;
    o[4]=v1.x; o[5]=v1.y; o[6]=v1.z; o[7]=v1.w;
    *(ushort8_t*)(Xt + (size_t)kl*16384 + (size_t)n*256 + cb + half*8) = o;
  }
}

// ---------------- KC: channel mix. Per block: 4 kl x 64 n x 64 f, K-loop over c ----------------
// R[kl][n][f] = sum_c X[kl][n][c] * K[f][c](kl),  K = sum_b dl[i][b] * wkb[kf][b][f][c].
// Direct-A global->reg; B double-buffered in LDS -> ONE barrier per cc; rolling wkb prefetch.
// XCD-chunked swizzle (HW round-robin bid&7 -> XCD): XCD x owns klg in [32x, 32x+32),
// f-siblings consecutive -> Xt rows fetched once/XCD, wkb slice (4 kf = 1.6 MB) L2-resident.
__global__ __launch_bounds__(512) void k_mix(const u16* __restrict__ Xt,
                                             const u16* __restrict__ wkb,
                                             const float* __restrict__ Dm,
                                             u16* __restrict__ R){
  __shared__ __bf16 Bl[2][4][64][40];
  int t = threadIdx.x;
  int orig = blockIdx.x;               // 0..1023, XCD = orig & 7 (round-robin)
  int wid  = (orig & 7)*128 + (orig >> 3);   // chunked: contiguous work per XCD
  int klg  = wid >> 2;                 // 0..255
  int fb   = (wid & 3) * 64;           // f base — siblings temporally adjacent
  int kl0 = klg * 4;
  int kf  = kl0 >> 5;                  // k (row frequency), shared by the 4 kl
  int lb  = kl0 & 31;                  // l base
  float dl[4][3];
  #pragma unroll
  for (int i = 0; i < 4; ++i){
    #pragma unroll
    for (int b = 0; b < 3; ++b) dl[i][b] = rfl_f(Dm[(lb+i)*32 + b]);
  }
  int lane = t & 63, wv = t >> 6;
  int kli = wv & 3, nh = wv >> 2;
  int l4 = lane & 15, g = lane >> 4;
  int rowi = t >> 3;             // 0..63 : f-local row for B-gen
  int cq   = t & 7;              // c-quad within 32-wide chunk
  f32x4 acc[2][4];
  #pragma unroll
  for (int m = 0; m < 2; ++m){
    #pragma unroll
    for (int nn = 0; nn < 4; ++nn){ f32x4 z={0.f,0.f,0.f,0.f}; acc[m][nn]=z; }
  }
  // per-lane global A-frag base: Xt[kl0+kli][nh*32 + l4][g*8]  (+16*256 for m=1)
  const u16* xb = Xt + (size_t)(kl0 + kli)*16384 + (size_t)(nh*32 + l4)*256 + g*8;
  const u16* wb = wkb + ((size_t)(kf*3) << 16) + ((fb + rowi) << 8) + cq*4;
  // prologue: wq[b] = wkb[kf][b][fb+rowi][cq*4 .. +3] for cc=0
  ushort4 wq[3];
  #pragma unroll
  for (int b = 0; b < 3; ++b) wq[b] = *(const ushort4*)(wb + ((size_t)b << 16));
  for (int cc = 0; cc < 8; ++cc){
    int p = cc & 1;
    // A-frags for THIS cc: latency hidden behind gen + barrier
    bf16x8 afc[2];
    afc[0] = *(const bf16x8*)(xb + cc*32);
    afc[1] = *(const bf16x8*)(xb + cc*32 + 16*256);
    // convert current wkb quads to f32; rolling reload for cc+1
    float tf[3][4];
    #pragma unroll
    for (int b = 0; b < 3; ++b){
      tf[b][0] = bf2f(wq[b].x); tf[b][1] = bf2f(wq[b].y);
      tf[b][2] = bf2f(wq[b].z); tf[b][3] = bf2f(wq[b].w);
    }
    if (cc < 7){
      const u16* wn = wb + (cc + 1)*32;
      #pragma unroll
      for (int b = 0; b < 3; ++b) wq[b] = *(const ushort4*)(wn + ((size_t)b << 16));
    }
    #pragma unroll
    for (int i = 0; i < 4; ++i){
      float s0 = dl[i][0]*tf[0][0] + dl[i][1]*tf[1][0] + dl[i][2]*tf[2][0];
      float s1 = dl[i][0]*tf[0][1] + dl[i][1]*tf[1][1] + dl[i][2]*tf[2][1];
      float s2 = dl[i][0]*tf[0][2] + dl[i][1]*tf[1][2] + dl[i][2]*tf[2][2];
      float s3 = dl[i][0]*tf[0][3] + dl[i][1]*tf[1][3] + dl[i][2]*tf[2][3];
      ushort4 pv;
      pv.x = bf16_bits(s0); pv.y = bf16_bits(s1);
      pv.z = bf16_bits(s2); pv.w = bf16_bits(s3);
      *(ushort4*)((u16*)&Bl[p][i][rowi][cq*4]) = pv;
    }
    __syncthreads();
    bf16x8 bfr[4];
    #pragma unroll
    for (int nn = 0; nn < 4; ++nn)
      bfr[nn] = *(const bf16x8*)&Bl[p][kli][nn*16 + l4][g*8];
    #pragma unroll
    for (int m = 0; m < 2; ++m){
      #pragma unroll
      for (int nn = 0; nn < 4; ++nn)
        acc[m][nn] = __builtin_amdgcn_mfma_f32_16x16x32_bf16(afc[m], bfr[nn], acc[m][nn], 0,0,0);
    }
  }
  // epilogue: R[kl][n][f] bf16 — f contiguous, 4x32B segments per store instr
  int kl = kl0 + kli;
  #pragma unroll
  for (int m = 0; m < 2; ++m){
    #pragma unroll
    for (int nn = 0; nn < 4; ++nn){
      #pragma unroll
      for (int r = 0; r < 4; ++r){
        int n = nh*32 + m*16 + g*4 + r;
        R[((size_t)kl*64 + n)*256 + fb + nn*16 + l4] = bf16_bits(acc[m][nn][r]);
      }
    }
  }
}

// ---------------- KD2: fused gather-transpose + IDCT + crop. Block = (n, 16 f) ----------------
__global__ __launch_bounds__(256) void k_idct2(const u16* __restrict__ R,
                                               const float* __restrict__ Mm,
                                               float* __restrict__ out){
  __shared__ __bf16 Mmb[32][40];
  __shared__ u16    st[1024][20];
  __shared__ __bf16 t2[4][32*40];
  int t = threadIdx.x;
  for (int idx = t; idx < 1024; idx += 256)
    Mmb[idx>>5][idx&31] = (__bf16)Mm[idx];
  int n = blockIdx.x, fbb = blockIdx.y * 16;
  #pragma unroll
  for (int rr = 0; rr < 8; ++rr){
    int kl = rr*128 + (t >> 1), half = t & 1;
    ushort8_t v = *(const ushort8_t*)(R + (size_t)kl*16384 + (size_t)n*256 + fbb + half*8);
    ushort4 a, b;
    a.x=v[0]; a.y=v[1]; a.z=v[2]; a.w=v[3];
    b.x=v[4]; b.y=v[5]; b.z=v[6]; b.w=v[7];
    *(ushort4*)&st[kl][half*8]     = a;
    *(ushort4*)&st[kl][half*8 + 4] = b;
  }
  __syncthreads();
  int wv = t>>6, lane = t&63, l4 = lane&15, g = lane>>4;
  bf16x8 mmf[2];
  mmf[0] = *(const bf16x8*)&Mmb[l4][g*8];
  mmf[1] = *(const bf16x8*)&Mmb[16+l4][g*8];
  f32x4 z = {0.f,0.f,0.f,0.f};
  __bf16* tw = t2[wv];
  for (int ci = 0; ci < 4; ++ci){
    int fl = wv*4 + ci;
    bf16x8 bfr[2];
    #pragma unroll
    for (int nn = 0; nn < 2; ++nn){
      #pragma unroll
      for (int jj = 0; jj < 8; ++jj)
        bfr[nn][jj] = __builtin_bit_cast(__bf16, st[(g*8+jj)*32 + nn*16 + l4][fl]);
    }
    #pragma unroll
    for (int m = 0; m < 2; ++m){
      #pragma unroll
      for (int nn = 0; nn < 2; ++nn){
        f32x4 d = __builtin_amdgcn_mfma_f32_16x16x32_bf16(mmf[m], bfr[nn], z, 0,0,0);
        #pragma unroll
        for (int r = 0; r < 4; ++r)
          tw[(m*16 + g*4 + r)*40 + nn*16 + l4] = (__bf16)d[r];
      }
    }
    bf16x8 a2[2];
    a2[0] = *(const bf16x8*)&tw[l4*40 + g*8];
    a2[1] = *(const bf16x8*)&tw[(16+l4)*40 + g*8];
    float* oo = out + (size_t)(n*256 + fbb + fl)*900;
    #pragma unroll
    for (int m2 = 0; m2 < 2; ++m2){
      #pragma unroll
      for (int nn2 = 0; nn2 < 2; ++nn2){
        f32x4 d = __builtin_amdgcn_mfma_f32_16x16x32_bf16(a2[m2], mmf[nn2], z, 0,0,0);
        #pragma unroll
        for (int r = 0; r < 4; ++r){
          int h = m2*16 + g*4 + r, w2 = nn2*16 + l4;
          if (h < 30 && w2 < 30) oo[h*30 + w2] = d[r];
        }
      }
    }
  }
}

// ---------------- launch ----------------
// ws layout (bytes) — peak 79,699,968:
//   Dm   @ 0          (4 KB)
//   Mm   @ 4096       (4 KB)
//   Xt   @ 8192       (33,554,432)   [kl][n][c] bf16
//   R    @ 33562624   (33,554,432)   [kl][n][f] bf16
//   wkb  @ 67117056   (12,582,912)   [kf][b][f][c] bf16
extern "C" void kernel_launch(void* const* d_in, const int* in_sizes, int n_in,
                              void* d_out, int out_size, void* d_ws, size_t ws_size,
                              hipStream_t stream){
  (void)in_sizes; (void)n_in; (void)out_size; (void)ws_size;
  const float* x  = (const float*)d_in[0];
  const float* w  = (const float*)d_in[1];
  float* out = (float*)d_out;
  char* ws = (char*)d_ws;
  float* Dm = (float*)(ws + 0);
  float* Mm = (float*)(ws + 4096);
  u16* Xt   = (u16*)(ws + 8192);
  u16* R    = (u16*)(ws + 33562624);
  u16* wkb  = (u16*)(ws + 67117056);

  hipLaunchKernelGGL(k_init,  dim3(1),        dim3(256), 0, stream, Dm, Mm);
  hipLaunchKernelGGL(k_wkb,   dim3(256,8),    dim3(256), 0, stream, w, Dm, wkb);
  hipLaunchKernelGGL(k_dct2,  dim3(64,16),    dim3(256), 0, stream, x, Dm, Xt);
  hipLaunchKernelGGL(k_mix,   dim3(1024),     dim3(512), 0, stream, Xt, wkb, Dm, R);
  hipLaunchKernelGGL(k_idct2, dim3(64,16),    dim3(256), 0, stream, R, Mm, out);
}

// Round 13
// 80.805 us; speedup vs baseline: 1.6432x; 1.0167x over previous
//
#include <hip/hip_runtime.h>
#include <hip/hip_bf16.h>

typedef __bf16 bf16x8 __attribute__((ext_vector_type(8)));
typedef float  f32x4  __attribute__((ext_vector_type(4)));
typedef unsigned short u16;
typedef u16 ushort8_t __attribute__((ext_vector_type(8)));

#define PI_D 3.14159265358979323846

__device__ __forceinline__ float rfl_f(float x){
  return __builtin_bit_cast(float, __builtin_amdgcn_readfirstlane(__builtin_bit_cast(int, x)));
}
__device__ __forceinline__ u16 bf16_bits(float f){
  __bf16 b = (__bf16)f;
  return __builtin_bit_cast(u16, b);
}
__device__ __forceinline__ float bf2f(u16 u){
  return __builtin_bit_cast(float, ((unsigned)u) << 16);
}

// ---------------- K0: DCT / IDCT matrices (32x32 each, f32) ----------------
// Dm[k][i] = 2*cos(pi*k*(2i+1)/64)          (DCT, freq-major rows)
// Mm[i][k] = cos(pi*k*(2i+1)/64) * w[k]     (IDCT, space-major rows), w0=1/64 else 1/32
__global__ void k_init(float* __restrict__ Dm, float* __restrict__ Mm){
  for (int idx = threadIdx.x; idx < 1024; idx += 256){
    int r = idx >> 5, c = idx & 31;
    Dm[idx] = (float)(2.0 * cos(PI_D * (double)r * (double)(2*c+1) / 64.0));
    Mm[idx] = (float)(cos(PI_D * (double)c * (double)(2*r+1) / 64.0) * ((c==0)?0.5:1.0) / 32.0);
  }
}

// ---------------- KW2: wkb[kf][b][f][c] = sum_a dk[kf][a] * w[f][c][a*3+b]  (bf16) ----------------
__global__ __launch_bounds__(256) void k_wkb(const float* __restrict__ w,
                                             const float* __restrict__ Dm,
                                             u16* __restrict__ wkb){
  __shared__ float dks[32][3];
  int t = threadIdx.x;
  if (t < 96) dks[t/3][t%3] = Dm[(t/3)*32 + (t%3)];
  __syncthreads();
  int f = blockIdx.x, kf0 = blockIdx.y*4, c = t;
  const float* s = w + ((size_t)f*256 + c)*9;
  float wv9[9];
  #pragma unroll
  for (int j = 0; j < 9; ++j) wv9[j] = s[j];
  #pragma unroll
  for (int kq = 0; kq < 4; ++kq){
    int kf = kf0 + kq;
    float d0 = dks[kf][0], d1 = dks[kf][1], d2 = dks[kf][2];
    #pragma unroll
    for (int b = 0; b < 3; ++b){
      float v = d0*wv9[b] + d1*wv9[3+b] + d2*wv9[6+b];
      wkb[((size_t)(kf*3 + b) << 16) + (f << 8) + c] = bf16_bits(v);
    }
  }
}

// ---------------- KA2: fused DCT + transpose-write, W-first, bulk-prefetched x ----------------
// X = DH·x·DW^T computed as (x·DW^T) then DH·(...). ALL x loads for the wave's 4 images
// are hoisted to the kernel top (16 x global_load_dwordx4 back-to-back, one exposed HBM
// latency) and converted into persistent A-fragments afA[4][2] (32 VGPR).
__global__ __launch_bounds__(256) void k_dct2(const float* __restrict__ x,
                                              const float* __restrict__ Dm,
                                              u16* __restrict__ Xt){
  __shared__ __bf16 Dmb[32][40];
  __shared__ __bf16 t1[4][32*40];
  __shared__ u16    st[1024][20];   // pad-20: row stride 40B = 10 dwords -> rotating banks
  int t = threadIdx.x;
  for (int idx = t; idx < 1024; idx += 256)
    Dmb[idx>>5][idx&31] = (__bf16)Dm[idx];
  int wv = t >> 6, lane = t & 63, l4 = lane & 15, g = lane >> 4;
  int n = blockIdx.x, cb = blockIdx.y * 16;
  // bulk prefetch: afA[ci][m] = bf16 of x[n][cb+wv*4+ci][(m*16+l4)*32 + g*8 ..+8]
  bf16x8 afA[4][2];
  #pragma unroll
  for (int ci = 0; ci < 4; ++ci){
    const float* xs = x + ((size_t)(n*256 + cb + wv*4 + ci)) * 1024;
    #pragma unroll
    for (int m = 0; m < 2; ++m){
      const float* xr = xs + (m*16 + l4)*32 + g*8;
      float4 v0 = *(const float4*)(xr);
      float4 v1 = *(const float4*)(xr + 4);
      afA[ci][m][0]=(__bf16)v0.x; afA[ci][m][1]=(__bf16)v0.y;
      afA[ci][m][2]=(__bf16)v0.z; afA[ci][m][3]=(__bf16)v0.w;
      afA[ci][m][4]=(__bf16)v1.x; afA[ci][m][5]=(__bf16)v1.y;
      afA[ci][m][6]=(__bf16)v1.z; afA[ci][m][7]=(__bf16)v1.w;
    }
  }
  __syncthreads();   // Dmb ready
  bf16x8 dmf[2];
  dmf[0] = *(const bf16x8*)&Dmb[l4][g*8];
  dmf[1] = *(const bf16x8*)&Dmb[16+l4][g*8];
  __bf16* tw = t1[wv];
  f32x4 z = {0.f,0.f,0.f,0.f};
  #pragma unroll
  for (int ci = 0; ci < 4; ++ci){
    int cl = wv*4 + ci;
    // phase 1: T1'[h][lf] = sum_w x[h][w]*DW[lf][w].  A = x rows (prefetched), B = Dm frag.
    #pragma unroll
    for (int m = 0; m < 2; ++m){
      #pragma unroll
      for (int nn = 0; nn < 2; ++nn){
        f32x4 d = __builtin_amdgcn_mfma_f32_16x16x32_bf16(afA[ci][m], dmf[nn], z, 0,0,0);
        // d[r] = T1'[h = m*16+g*4+r][lf = nn*16+l4]; store transposed: t1[lf][h]
        #pragma unroll
        for (int r = 0; r < 4; ++r)
          tw[(nn*16 + l4)*40 + m*16 + g*4 + r] = (__bf16)d[r];
      }
    }
    // phase 2: X[kf][lf] = sum_h DH[kf][h]*T1'[h][lf].  A = Dm frag, B = t1[lf][g*8..] (b128).
    bf16x8 b2[2];
    b2[0] = *(const bf16x8*)&tw[(l4)*40 + g*8];
    b2[1] = *(const bf16x8*)&tw[(16+l4)*40 + g*8];
    #pragma unroll
    for (int m2 = 0; m2 < 2; ++m2){
      #pragma unroll
      for (int nn2 = 0; nn2 < 2; ++nn2){
        f32x4 d = __builtin_amdgcn_mfma_f32_16x16x32_bf16(dmf[m2], b2[nn2], z, 0,0,0);
        #pragma unroll
        for (int r = 0; r < 4; ++r){
          int kk = m2*16 + g*4 + r, ll = nn2*16 + l4;
          st[kk*32 + ll][cl] = bf16_bits(d[r]);
        }
      }
    }
  }
  __syncthreads();
  #pragma unroll
  for (int rr = 0; rr < 8; ++rr){
    int kl = rr*128 + (t >> 1), half = t & 1;
    ushort4 v0 = *(const ushort4*)&st[kl][half*8];
    ushort4 v1 = *(const ushort4*)&st[kl][half*8 + 4];
    ushort8_t o;
    o[0]=v0.x; o[1]=v0.y; o[2]=v0.z; o[3]=v0.w;
    o[4]=v1.x; o[5]=v1.y; o[6]=v1.z; o[7]=v1.w;
    *(ushort8_t*)(Xt + (size_t)kl*16384 + (size_t)n*256 + cb + half*8) = o;
  }
}

// ---------------- KC: channel mix. Per block: 4 kl x 64 n x 64 f, K-loop over c ----------------
// R[kl][n][f] = sum_c X[kl][n][c] * K[f][c](kl),  K = sum_b dl[i][b] * wkb[kf][b][f][c].
// Direct-A global->reg; B double-buffered in LDS -> ONE barrier per cc; rolling wkb prefetch.
// XCD-chunked swizzle (HW round-robin bid&7 -> XCD): XCD x owns klg in [32x, 32x+32),
// f-siblings consecutive -> Xt rows fetched once/XCD, wkb slice (4 kf = 1.6 MB) L2-resident.
__global__ __launch_bounds__(512) void k_mix(const u16* __restrict__ Xt,
                                             const u16* __restrict__ wkb,
                                             const float* __restrict__ Dm,
                                             u16* __restrict__ R){
  __shared__ __bf16 Bl[2][4][64][40];
  int t = threadIdx.x;
  int orig = blockIdx.x;               // 0..1023, XCD = orig & 7 (round-robin)
  int wid  = (orig & 7)*128 + (orig >> 3);   // chunked: contiguous work per XCD
  int klg  = wid >> 2;                 // 0..255
  int fb   = (wid & 3) * 64;           // f base — siblings temporally adjacent
  int kl0 = klg * 4;
  int kf  = kl0 >> 5;                  // k (row frequency), shared by the 4 kl
  int lb  = kl0 & 31;                  // l base
  float dl[4][3];
  #pragma unroll
  for (int i = 0; i < 4; ++i){
    #pragma unroll
    for (int b = 0; b < 3; ++b) dl[i][b] = rfl_f(Dm[(lb+i)*32 + b]);
  }
  int lane = t & 63, wv = t >> 6;
  int kli = wv & 3, nh = wv >> 2;
  int l4 = lane & 15, g = lane >> 4;
  int rowi = t >> 3;             // 0..63 : f-local row for B-gen
  int cq   = t & 7;              // c-quad within 32-wide chunk
  f32x4 acc[2][4];
  #pragma unroll
  for (int m = 0; m < 2; ++m){
    #pragma unroll
    for (int nn = 0; nn < 4; ++nn){ f32x4 z={0.f,0.f,0.f,0.f}; acc[m][nn]=z; }
  }
  // per-lane global A-frag base: Xt[kl0+kli][nh*32 + l4][g*8]  (+16*256 for m=1)
  const u16* xb = Xt + (size_t)(kl0 + kli)*16384 + (size_t)(nh*32 + l4)*256 + g*8;
  const u16* wb = wkb + ((size_t)(kf*3) << 16) + ((fb + rowi) << 8) + cq*4;
  // prologue: wq[b] = wkb[kf][b][fb+rowi][cq*4 .. +3] for cc=0
  ushort4 wq[3];
  #pragma unroll
  for (int b = 0; b < 3; ++b) wq[b] = *(const ushort4*)(wb + ((size_t)b << 16));
  for (int cc = 0; cc < 8; ++cc){
    int p = cc & 1;
    // A-frags for THIS cc: latency hidden behind gen + barrier
    bf16x8 afc[2];
    afc[0] = *(const bf16x8*)(xb + cc*32);
    afc[1] = *(const bf16x8*)(xb + cc*32 + 16*256);
    // convert current wkb quads to f32; rolling reload for cc+1
    float tf[3][4];
    #pragma unroll
    for (int b = 0; b < 3; ++b){
      tf[b][0] = bf2f(wq[b].x); tf[b][1] = bf2f(wq[b].y);
      tf[b][2] = bf2f(wq[b].z); tf[b][3] = bf2f(wq[b].w);
    }
    if (cc < 7){
      const u16* wn = wb + (cc + 1)*32;
      #pragma unroll
      for (int b = 0; b < 3; ++b) wq[b] = *(const ushort4*)(wn + ((size_t)b << 16));
    }
    #pragma unroll
    for (int i = 0; i < 4; ++i){
      float s0 = dl[i][0]*tf[0][0] + dl[i][1]*tf[1][0] + dl[i][2]*tf[2][0];
      float s1 = dl[i][0]*tf[0][1] + dl[i][1]*tf[1][1] + dl[i][2]*tf[2][1];
      float s2 = dl[i][0]*tf[0][2] + dl[i][1]*tf[1][2] + dl[i][2]*tf[2][2];
      float s3 = dl[i][0]*tf[0][3] + dl[i][1]*tf[1][3] + dl[i][2]*tf[2][3];
      ushort4 pv;
      pv.x = bf16_bits(s0); pv.y = bf16_bits(s1);
      pv.z = bf16_bits(s2); pv.w = bf16_bits(s3);
      *(ushort4*)((u16*)&Bl[p][i][rowi][cq*4]) = pv;
    }
    __syncthreads();
    bf16x8 bfr[4];
    #pragma unroll
    for (int nn = 0; nn < 4; ++nn)
      bfr[nn] = *(const bf16x8*)&Bl[p][kli][nn*16 + l4][g*8];
    #pragma unroll
    for (int m = 0; m < 2; ++m){
      #pragma unroll
      for (int nn = 0; nn < 4; ++nn)
        acc[m][nn] = __builtin_amdgcn_mfma_f32_16x16x32_bf16(afc[m], bfr[nn], acc[m][nn], 0,0,0);
    }
  }
  // epilogue: R[kl][n][f] bf16 — f contiguous, 4x32B segments per store instr
  int kl = kl0 + kli;
  #pragma unroll
  for (int m = 0; m < 2; ++m){
    #pragma unroll
    for (int nn = 0; nn < 4; ++nn){
      #pragma unroll
      for (int r = 0; r < 4; ++r){
        int n = nh*32 + m*16 + g*4 + r;
        R[((size_t)kl*64 + n)*256 + fb + nn*16 + l4] = bf16_bits(acc[m][nn][r]);
      }
    }
  }
}

// ---------------- KD2: fused gather-transpose + IDCT + crop. Block = (n, 16 f) ----------------
__global__ __launch_bounds__(256) void k_idct2(const u16* __restrict__ R,
                                               const float* __restrict__ Mm,
                                               float* __restrict__ out){
  __shared__ __bf16 Mmb[32][40];
  __shared__ u16    st[1024][20];
  __shared__ __bf16 t2[4][32*40];
  int t = threadIdx.x;
  for (int idx = t; idx < 1024; idx += 256)
    Mmb[idx>>5][idx&31] = (__bf16)Mm[idx];
  int n = blockIdx.x, fbb = blockIdx.y * 16;
  #pragma unroll
  for (int rr = 0; rr < 8; ++rr){
    int kl = rr*128 + (t >> 1), half = t & 1;
    ushort8_t v = *(const ushort8_t*)(R + (size_t)kl*16384 + (size_t)n*256 + fbb + half*8);
    ushort4 a, b;
    a.x=v[0]; a.y=v[1]; a.z=v[2]; a.w=v[3];
    b.x=v[4]; b.y=v[5]; b.z=v[6]; b.w=v[7];
    *(ushort4*)&st[kl][half*8]     = a;
    *(ushort4*)&st[kl][half*8 + 4] = b;
  }
  __syncthreads();
  int wv = t>>6, lane = t&63, l4 = lane&15, g = lane>>4;
  bf16x8 mmf[2];
  mmf[0] = *(const bf16x8*)&Mmb[l4][g*8];
  mmf[1] = *(const bf16x8*)&Mmb[16+l4][g*8];
  f32x4 z = {0.f,0.f,0.f,0.f};
  __bf16* tw = t2[wv];
  for (int ci = 0; ci < 4; ++ci){
    int fl = wv*4 + ci;
    bf16x8 bfr[2];
    #pragma unroll
    for (int nn = 0; nn < 2; ++nn){
      #pragma unroll
      for (int jj = 0; jj < 8; ++jj)
        bfr[nn][jj] = __builtin_bit_cast(__bf16, st[(g*8+jj)*32 + nn*16 + l4][fl]);
    }
    #pragma unroll
    for (int m = 0; m < 2; ++m){
      #pragma unroll
      for (int nn = 0; nn < 2; ++nn){
        f32x4 d = __builtin_amdgcn_mfma_f32_16x16x32_bf16(mmf[m], bfr[nn], z, 0,0,0);
        #pragma unroll
        for (int r = 0; r < 4; ++r)
          tw[(m*16 + g*4 + r)*40 + nn*16 + l4] = (__bf16)d[r];
      }
    }
    bf16x8 a2[2];
    a2[0] = *(const bf16x8*)&tw[l4*40 + g*8];
    a2[1] = *(const bf16x8*)&tw[(16+l4)*40 + g*8];
    float* oo = out + (size_t)(n*256 + fbb + fl)*900;
    #pragma unroll
    for (int m2 = 0; m2 < 2; ++m2){
      #pragma unroll
      for (int nn2 = 0; nn2 < 2; ++nn2){
        f32x4 d = __builtin_amdgcn_mfma_f32_16x16x32_bf16(a2[m2], mmf[nn2], z, 0,0,0);
        #pragma unroll
        for (int r = 0; r < 4; ++r){
          int h = m2*16 + g*4 + r, w2 = nn2*16 + l4;
          if (h < 30 && w2 < 30) oo[h*30 + w2] = d[r];
        }
      }
    }
  }
}

// ---------------- launch ----------------
// ws layout (bytes) — peak 79,699,968:
//   Dm   @ 0          (4 KB)
//   Mm   @ 4096       (4 KB)
//   Xt   @ 8192       (33,554,432)   [kl][n][c] bf16
//   R    @ 33562624   (33,554,432)   [kl][n][f] bf16
//   wkb  @ 67117056   (12,582,912)   [kf][b][f][c] bf16
extern "C" void kernel_launch(void* const* d_in, const int* in_sizes, int n_in,
                              void* d_out, int out_size, void* d_ws, size_t ws_size,
                              hipStream_t stream){
  (void)in_sizes; (void)n_in; (void)out_size; (void)ws_size;
  const float* x  = (const float*)d_in[0];
  const float* w  = (const float*)d_in[1];
  float* out = (float*)d_out;
  char* ws = (char*)d_ws;
  float* Dm = (float*)(ws + 0);
  float* Mm = (float*)(ws + 4096);
  u16* Xt   = (u16*)(ws + 8192);
  u16* R    = (u16*)(ws + 33562624);
  u16* wkb  = (u16*)(ws + 67117056);

  hipLaunchKernelGGL(k_init,  dim3(1),        dim3(256), 0, stream, Dm, Mm);
  hipLaunchKernelGGL(k_wkb,   dim3(256,8),    dim3(256), 0, stream, w, Dm, wkb);
  hipLaunchKernelGGL(k_dct2,  dim3(64,16),    dim3(256), 0, stream, x, Dm, Xt);
  hipLaunchKernelGGL(k_mix,   dim3(1024),     dim3(512), 0, stream, Xt, wkb, Dm, R);
  hipLaunchKernelGGL(k_idct2, dim3(64,16),    dim3(256), 0, stream, R, Mm, out);
}